// Round 7
// baseline (173.299 us; speedup 1.0000x reference)
//
#include <hip/hip_runtime.h>
#include <hip/hip_cooperative_groups.h>

namespace cg = cooperative_groups;

// NaiveCollider: uniform-grid broad phase, exact jnp.nonzero ordered-compaction
// semantics. ONE cooperative dispatch (96 blocks x 256 = 24576 threads), 4 grid
// syncs replacing 5 graph nodes (~4us/node boundary):
//   P0 zero cell counters | P1 fill cells + out=centers | P2 count (3 thr/body)
//   P3 scan (block 0: double row-scan, status, wave-parallel boundary resolve)
//   P4 resolve fast rows (3 thr/body)
// Harness floor: ~40us d_ws 0xAA re-poison + ~25us tiny reset dispatches.

constexpr int NB = 8192;
constexpr int GRID_DIM = 56;              // cell 2.0 >= max rsum; 112/2
constexpr int NCELLS = GRID_DIM * GRID_DIM;
constexpr int CAP = 20;                   // max bodies/cell (Poisson mean 2.6)
constexpr float INV_CELL = 0.5f;
constexpr float EPS = 1e-12f;

// workspace int offsets
constexpr int O_CCOUNT = 0;                        // 3136
constexpr int O_RCOMB  = O_CCOUNT + NCELLS;        // 8192 (16B-aligned: 3136*4)
constexpr int O_STATUS = O_RCOMB + NB;             // 8192
constexpr int O_CELLS  = (O_STATUS + NB + 3) & ~3; // float4[NCELLS*CAP] ~1MB

__device__ __forceinline__ int cell_of(float v) {
    int c = (int)(v * INV_CELL);
    return c > GRID_DIM - 1 ? GRID_DIM - 1 : (c < 0 ? 0 : c);
}

__device__ __forceinline__ int wave_incl_scan(int v, int lane) {
#pragma unroll
    for (int off = 1; off < 64; off <<= 1) {
        int y = __shfl_up(v, off);
        if (lane >= off) v += y;
    }
    return v;
}

// Serial fallback: hit count of a broad-cap boundary row (unreached when
// total broad pairs <= LB, which holds for this input).
__device__ int slow_boundary_hits(const int* ccount, const float4* cells,
                                  const float2* centers, const float* radii,
                                  int i, int lim) {
    const float2 ci = centers[i];
    const float ri = radii[i];
    const int cx = cell_of(ci.x), cy = cell_of(ci.y);
    const int x0 = max(cx - 1, 0), x1 = min(cx + 1, GRID_DIM - 1);
    const int y0 = max(cy - 1, 0), y1 = min(cy + 1, GRID_DIM - 1);
    int h = 0;
    for (int yy = y0; yy <= y1; ++yy)
        for (int xx = x0; xx <= x1; ++xx) {
            const int c = yy * GRID_DIM + xx;
            const int n = min(ccount[c], CAP);
            for (int k = 0; k < n; ++k) {
                const float4 o = cells[c * CAP + k];
                const int j = __float_as_int(o.w);
                if (j <= i) continue;
                const float rs = ri + o.z, dx = o.x - ci.x, dy = o.y - ci.y;
                if (!(fabsf(dx) <= rs && fabsf(dy) <= rs)) continue;
                int brank = 0;
                for (int yy2 = y0; yy2 <= y1; ++yy2)
                    for (int xx2 = x0; xx2 <= x1; ++xx2) {
                        const int c2 = yy2 * GRID_DIM + xx2;
                        const int n2 = min(ccount[c2], CAP);
                        for (int k2 = 0; k2 < n2; ++k2) {
                            const float4 o2 = cells[c2 * CAP + k2];
                            const int j2 = __float_as_int(o2.w);
                            if (j2 <= i || j2 >= j) continue;
                            const float rs2 = ri + o2.z;
                            if (fabsf(o2.x - ci.x) <= rs2 && fabsf(o2.y - ci.y) <= rs2)
                                ++brank;
                        }
                    }
                if (brank < lim && rs - sqrtf(dx * dx + dy * dy + EPS) > 0.f) ++h;
            }
        }
    return h;
}

__global__ __launch_bounds__(256) void fused_kernel(
        const float2* __restrict__ centers, const float* __restrict__ radii,
        const int* __restrict__ LBp, const int* __restrict__ LNp,
        int* __restrict__ ccount, float4* __restrict__ cells,
        int* __restrict__ rcomb, int* __restrict__ status,
        float* __restrict__ out) {
    cg::grid_group grid = cg::this_grid();
    __shared__ int sh_hc[NB];   // 32 KB: per-row hit counts (block 0 scan)
    __shared__ int wsum[4];
    __shared__ int spec_n;
    __shared__ int spec_row[2], spec_bst[2], spec_h0[2];

    const int t = blockIdx.x * 256 + threadIdx.x;   // 0..24575

    // ---- P0: zero cell counters ----
    if (t < NCELLS) ccount[t] = 0;
    grid.sync();

    // ---- P1: fill cells + rcomb=0 + out=centers ----
    if (t < NB) {
        const float2 c = centers[t];
        const float r = radii[t];
        ((float2*)out)[t] = c;
        rcomb[t] = 0;
        const int cell = cell_of(c.y) * GRID_DIM + cell_of(c.x);
        const int slot = atomicAdd(&ccount[cell], 1);
        if (slot < CAP)
            cells[cell * CAP + slot] = make_float4(c.x, c.y, r, __int_as_float(t));
    }
    grid.sync();

    // ---- P2: count, 3 threads/body (one per y-row of 3x3 hood) ----
    {
        const int i = t & (NB - 1);
        const int seg = t >> 13;
        const float2 ci = centers[i];
        const float ri = radii[i];
        const int cx = cell_of(ci.x), cy = cell_of(ci.y);
        const int yy = cy - 1 + seg;
        if (yy >= 0 && yy < GRID_DIM) {
            const int x0 = max(cx - 1, 0), x1 = min(cx + 1, GRID_DIM - 1);
            int rc = 0, hc = 0;
            for (int xx = x0; xx <= x1; ++xx) {
                const int c = yy * GRID_DIM + xx;
                const int n = min(ccount[c], CAP);
                const float4* p = cells + c * CAP;
                for (int k = 0; k < n; ++k) {
                    const float4 o = p[k];
                    if (__float_as_int(o.w) <= i) continue;
                    const float rs = ri + o.z;
                    const float dx = o.x - ci.x, dy = o.y - ci.y;
                    if (fabsf(dx) <= rs && fabsf(dy) <= rs) {
                        ++rc;
                        if (rs - sqrtf(dx * dx + dy * dy + EPS) > 0.f) ++hc;
                    }
                }
            }
            if (rc | hc) atomicAdd(&rcomb[i], (rc << 8) | hc);
        }
    }
    grid.sync();

    // ---- P3: block 0 does both row scans + status + boundary resolve ----
    if (blockIdx.x == 0) {
        const int lane = threadIdx.x & 63, wid = threadIdx.x >> 6;
        const int LB = *LBp, LN = *LNp;
        if (threadIdx.x == 0) spec_n = 0;
        const int base = threadIdx.x * 32;
        // pass A: per-thread broad sum -> block exclusive scan
        int rsum = 0;
        for (int k = 0; k < 32; k += 4) {
            const int4 v = *(const int4*)&rcomb[base + k];
            rsum += (v.x >> 8) + (v.y >> 8) + (v.z >> 8) + (v.w >> 8);
        }
        const int incl = wave_incl_scan(rsum, lane);
        if (lane == 63) wsum[wid] = incl;
        __syncthreads();
        if (wid == 0) {
            const int orig = (lane < 4) ? wsum[lane] : 0;
            const int inc = wave_incl_scan(orig, lane);
            if (lane < 4) wsum[lane] = inc - orig;
        }
        __syncthreads();
        const int runb0 = wsum[wid] + incl - rsum;
        // pass B: per-row hit counts (boundary rows via slow path), hit sum
        int runb = runb0;
        int hsum = 0;
        for (int k = 0; k < 32; ++k) {
            const int i = base + k;
            const int v = rcomb[i];
            const int rc = v >> 8, hr = v & 0xff;
            int hc;
            if (runb >= LB) hc = 0;
            else if (runb + rc <= LB) hc = hr;
            else hc = slow_boundary_hits(ccount, cells, centers, radii, i, LB - runb);
            sh_hc[i] = hc;
            hsum += hc;
            runb += rc;
        }
        __syncthreads();  // wsum reuse
        const int incl2 = wave_incl_scan(hsum, lane);
        if (lane == 63) wsum[wid] = incl2;
        __syncthreads();
        if (wid == 0) {
            const int orig = (lane < 4) ? wsum[lane] : 0;
            const int inc = wave_incl_scan(orig, lane);
            if (lane < 4) wsum[lane] = inc - orig;
        }
        __syncthreads();
        int runh = wsum[wid] + incl2 - hsum;
        // pass C: status + spec capture
        runb = runb0;
        for (int k = 0; k < 32; ++k) {
            const int i = base + k;
            const int rc = rcomb[i] >> 8;
            const int hc = sh_hc[i];
            const int h0 = runh;
            int st = 0;
            if (hc > 0 && h0 < LN) {
                const bool bfast = (runb + rc <= LB);
                const bool nfast = (h0 + hc <= LN);
                if (bfast && nfast) st = 1;
                else {
                    const int n = atomicAdd(&spec_n, 1);
                    if (n < 2) { spec_row[n] = i; spec_bst[n] = runb; spec_h0[n] = h0; }
                }
            }
            status[i] = st;
            runb += rc;
            runh += hc;
        }
        __syncthreads();
        // wave 0: exact j-ordered rank resolve for the <=2 boundary rows
        if (threadIdx.x < 64) {
            const int ns = min(spec_n, 2);
            for (int sp = 0; sp < ns; ++sp) {
                const int i = spec_row[sp];
                const int blim = LB - spec_bst[sp];
                const int h0 = spec_h0[sp];
                const float2 ci = centers[i];
                const float ri = radii[i];
                const int cx = cell_of(ci.x), cy = cell_of(ci.y);
                const int x0 = max(cx - 1, 0), x1 = min(cx + 1, GRID_DIM - 1);
                const int y0 = max(cy - 1, 0), y1 = min(cy + 1, GRID_DIM - 1);
                int seg0[9], slen[9], nseg = 0, K = 0;
                for (int yy = y0; yy <= y1; ++yy)
                    for (int xx = x0; xx <= x1; ++xx) {
                        const int c = yy * GRID_DIM + xx;
                        const int n = min(ccount[c], CAP);
                        if (n > 0) { seg0[nseg] = c * CAP; slen[nseg] = n; K += n; ++nseg; }
                    }
                float accx = 0.f, accy = 0.f;
                for (int cb = 0; cb < K; cb += 64) {
                    const int e = cb + lane;
                    const bool ok = e < K;
                    int s = 0;
                    if (ok) {
                        int r = e;
                        for (int g = 0; g < nseg; ++g) {
                            if (r < slen[g]) { s = seg0[g] + r; break; }
                            r -= slen[g];
                        }
                    }
                    const float4 o = ok ? cells[s] : make_float4(0, 0, 0, __int_as_float(-1));
                    const int j = __float_as_int(o.w);
                    const float rs = ri + o.z, dx = o.x - ci.x, dy = o.y - ci.y;
                    const bool ov = ok && j > i && fabsf(dx) <= rs && fabsf(dy) <= rs;
                    if (ov) {
                        const float dist = sqrtf(dx * dx + dy * dy + EPS);
                        const float depth = rs - dist;
                        int brank = 0, hrank = 0;
                        for (int e2 = 0; e2 < K; ++e2) {  // uniform, broadcast loads
                            int r2 = e2, s2 = 0;
                            for (int g = 0; g < nseg; ++g) {
                                if (r2 < slen[g]) { s2 = seg0[g] + r2; break; }
                                r2 -= slen[g];
                            }
                            const float4 o2 = cells[s2];
                            const int j2 = __float_as_int(o2.w);
                            if (j2 <= i || j2 >= j) continue;
                            const float rs2 = ri + o2.z;
                            const float dx2 = o2.x - ci.x, dy2 = o2.y - ci.y;
                            if (fabsf(dx2) <= rs2 && fabsf(dy2) <= rs2) {
                                ++brank;
                                if (rs2 - sqrtf(dx2 * dx2 + dy2 * dy2 + EPS) > 0.f) ++hrank;
                            }
                        }
                        if (depth > 0.f && brank < blim && h0 + hrank < LN) {
                            const float sc = 0.5f * depth / dist;
                            const float px = sc * dx, py = sc * dy;
                            accx -= px; accy -= py;
                            atomicAdd(&out[2 * j], px);
                            atomicAdd(&out[2 * j + 1], py);
                        }
                    }
                }
#pragma unroll
                for (int off = 32; off > 0; off >>= 1) {
                    accx += __shfl_down(accx, off);
                    accy += __shfl_down(accy, off);
                }
                if (lane == 0 && (accx != 0.f || accy != 0.f)) {
                    atomicAdd(&out[2 * i], accx);
                    atomicAdd(&out[2 * i + 1], accy);
                }
            }
        }
    }
    grid.sync();

    // ---- P4: resolve fast rows, 3 threads/body ----
    {
        const int i = t & (NB - 1);
        const int seg = t >> 13;
        if (status[i]) {
            const float2 ci = centers[i];
            const float ri = radii[i];
            const int cx = cell_of(ci.x), cy = cell_of(ci.y);
            const int yy = cy - 1 + seg;
            if (yy >= 0 && yy < GRID_DIM) {
                const int x0 = max(cx - 1, 0), x1 = min(cx + 1, GRID_DIM - 1);
                float accx = 0.f, accy = 0.f;
                for (int xx = x0; xx <= x1; ++xx) {
                    const int c = yy * GRID_DIM + xx;
                    const int n = min(ccount[c], CAP);
                    const float4* p = cells + c * CAP;
                    for (int k = 0; k < n; ++k) {
                        const float4 o = p[k];
                        const int j = __float_as_int(o.w);
                        if (j <= i) continue;
                        const float rs = ri + o.z;
                        const float dx = o.x - ci.x, dy = o.y - ci.y;
                        if (!(fabsf(dx) <= rs && fabsf(dy) <= rs)) continue;
                        const float dist = sqrtf(dx * dx + dy * dy + EPS);
                        const float depth = rs - dist;
                        if (depth <= 0.f) continue;
                        const float sc = 0.5f * depth / dist;
                        const float px = sc * dx, py = sc * dy;
                        accx -= px; accy -= py;
                        atomicAdd(&out[2 * j], px);
                        atomicAdd(&out[2 * j + 1], py);
                    }
                }
                if (accx != 0.f || accy != 0.f) {
                    atomicAdd(&out[2 * i], accx);
                    atomicAdd(&out[2 * i + 1], accy);
                }
            }
        }
    }
}

extern "C" void kernel_launch(void* const* d_in, const int* in_sizes, int n_in,
                              void* d_out, int out_size, void* d_ws, size_t ws_size,
                              hipStream_t stream) {
    const float2* centers = (const float2*)d_in[0];
    const float* radii    = (const float*)d_in[1];
    const int* LBp = (const int*)d_in[2];
    const int* LNp = (const int*)d_in[3];
    float* out = (float*)d_out;

    int* ws = (int*)d_ws;
    int* ccount = ws + O_CCOUNT;
    int* rcomb  = ws + O_RCOMB;
    int* status = ws + O_STATUS;
    float4* cells = (float4*)(ws + O_CELLS);

    void* args[] = {(void*)&centers, (void*)&radii, (void*)&LBp, (void*)&LNp,
                    (void*)&ccount, (void*)&cells, (void*)&rcomb, (void*)&status,
                    (void*)&out};
    hipLaunchCooperativeKernel((const void*)fused_kernel, dim3(96), dim3(256),
                               args, 0, stream);
}

// Round 8
// 107.257 us; speedup vs baseline: 1.6157x; 1.6157x over previous
//
#include <hip/hip_runtime.h>

// NaiveCollider: uniform-grid broad phase, exact jnp.nonzero ordered-compaction
// semantics. 4 graph nodes:
//   memset (12.5KB) : zero per-cell counters
//   fill   (wide)   : bin bodies into fixed-cap cell table, rcomb=0, out=centers
//   count  (wide)   : 3 threads/body (y-rows of 3x3 hood), packed (rc<<8|hc)
//                     atomicAdd into rcomb[body]
//   final  (96 blk) : EVERY block redundantly scans all 8192 packed counts
//                     (L2-shared, ~1-2us in parallel) -> status for its own
//                     86-row slice -> fast-row resolve; owner block's wave 0
//                     exact-resolves the <=2 truncation-boundary rows.
// R7 lesson: cooperative grid.sync costs ~20us/sync on 8-XCD MI355X (98.7us
// fused vs ~15us of work) — graph nodes (~5us) beat grid sync. Harness floor:
// ~40us d_ws 0xAA re-poison (268MB @ 85% peak) + ~25-30us reset dispatches.

constexpr int NB = 8192;
constexpr int GRID_DIM = 56;              // cell 2.0 >= max rsum; 112/2
constexpr int NCELLS = GRID_DIM * GRID_DIM;
constexpr int CAP = 20;                   // max bodies/cell (Poisson mean 2.6)
constexpr int NBLK = 96;                  // final_kernel blocks
constexpr int RPB = (NB + NBLK - 1) / NBLK;  // 86 rows per block
constexpr float INV_CELL = 0.5f;
constexpr float EPS = 1e-12f;

// workspace int offsets
constexpr int O_CCOUNT = 0;                        // 3136
constexpr int O_RCOMB  = O_CCOUNT + NCELLS;        // 8192 (byte off 12544, 16B-aligned)
constexpr int O_CELLS  = (O_RCOMB + NB + 3) & ~3;  // float4[NCELLS*CAP] ~1MB

__device__ __forceinline__ int cell_of(float v) {
    int c = (int)(v * INV_CELL);
    return c > GRID_DIM - 1 ? GRID_DIM - 1 : (c < 0 ? 0 : c);
}

__device__ __forceinline__ int wave_incl_scan(int v, int lane) {
#pragma unroll
    for (int off = 1; off < 64; off <<= 1) {
        int y = __shfl_up(v, off);
        if (lane >= off) v += y;
    }
    return v;
}

__global__ void fill_kernel(const float2* __restrict__ centers,
                            const float* __restrict__ radii,
                            int* __restrict__ ccount,
                            float4* __restrict__ cells,
                            int* __restrict__ rcomb,
                            float2* __restrict__ out2) {
    const int t = blockIdx.x * blockDim.x + threadIdx.x;
    if (t >= NB) return;
    const float2 c = centers[t];
    const float r = radii[t];
    out2[t] = c;        // fused out = centers copy
    rcomb[t] = 0;       // zero packed-count accumulator (used next dispatch)
    const int cell = cell_of(c.y) * GRID_DIM + cell_of(c.x);
    const int slot = atomicAdd(&ccount[cell], 1);
    if (slot < CAP)
        cells[cell * CAP + slot] = make_float4(c.x, c.y, r, __int_as_float(t));
}

// 3 threads/body: thread (seg, body) scans y-row cy-1+seg of the 3x3 hood.
__global__ void count_kernel(const float2* __restrict__ centers,
                             const float* __restrict__ radii,
                             const int* __restrict__ ccount,
                             const float4* __restrict__ cells,
                             int* __restrict__ rcomb) {
    const int t = blockIdx.x * blockDim.x + threadIdx.x;
    if (t >= 3 * NB) return;
    const int i = t & (NB - 1);
    const int seg = t >> 13;
    const float2 ci = centers[i];
    const float ri = radii[i];
    const int cx = cell_of(ci.x), cy = cell_of(ci.y);
    const int yy = cy - 1 + seg;
    if (yy < 0 || yy >= GRID_DIM) return;
    const int x0 = max(cx - 1, 0), x1 = min(cx + 1, GRID_DIM - 1);
    int rc = 0, hc = 0;
    for (int xx = x0; xx <= x1; ++xx) {
        const int c = yy * GRID_DIM + xx;
        const int n = min(ccount[c], CAP);
        const float4* p = cells + c * CAP;
        for (int k = 0; k < n; ++k) {
            const float4 o = p[k];
            if (__float_as_int(o.w) <= i) continue;
            const float rs = ri + o.z;
            const float dx = o.x - ci.x, dy = o.y - ci.y;
            if (fabsf(dx) <= rs && fabsf(dy) <= rs) {
                ++rc;
                if (rs - sqrtf(dx * dx + dy * dy + EPS) > 0.f) ++hc;
            }
        }
    }
    if (rc | hc) atomicAdd(&rcomb[i], (rc << 8) | hc);
}

// Serial fallback: hit count of a broad-cap boundary row (unreached when
// total broad pairs <= LB, which holds for this input).
__device__ int slow_boundary_hits(const int* ccount, const float4* cells,
                                  const float2* centers, const float* radii,
                                  int i, int lim) {
    const float2 ci = centers[i];
    const float ri = radii[i];
    const int cx = cell_of(ci.x), cy = cell_of(ci.y);
    const int x0 = max(cx - 1, 0), x1 = min(cx + 1, GRID_DIM - 1);
    const int y0 = max(cy - 1, 0), y1 = min(cy + 1, GRID_DIM - 1);
    int h = 0;
    for (int yy = y0; yy <= y1; ++yy)
        for (int xx = x0; xx <= x1; ++xx) {
            const int c = yy * GRID_DIM + xx;
            const int n = min(ccount[c], CAP);
            for (int k = 0; k < n; ++k) {
                const float4 o = cells[c * CAP + k];
                const int j = __float_as_int(o.w);
                if (j <= i) continue;
                const float rs = ri + o.z, dx = o.x - ci.x, dy = o.y - ci.y;
                if (!(fabsf(dx) <= rs && fabsf(dy) <= rs)) continue;
                int brank = 0;
                for (int yy2 = y0; yy2 <= y1; ++yy2)
                    for (int xx2 = x0; xx2 <= x1; ++xx2) {
                        const int c2 = yy2 * GRID_DIM + xx2;
                        const int n2 = min(ccount[c2], CAP);
                        for (int k2 = 0; k2 < n2; ++k2) {
                            const float4 o2 = cells[c2 * CAP + k2];
                            const int j2 = __float_as_int(o2.w);
                            if (j2 <= i || j2 >= j) continue;
                            const float rs2 = ri + o2.z;
                            if (fabsf(o2.x - ci.x) <= rs2 && fabsf(o2.y - ci.y) <= rs2)
                                ++brank;
                        }
                    }
                if (brank < lim && rs - sqrtf(dx * dx + dy * dy + EPS) > 0.f) ++h;
            }
        }
    return h;
}

__global__ __launch_bounds__(256) void final_kernel(
        const float2* __restrict__ centers, const float* __restrict__ radii,
        const int* __restrict__ ccount, const float4* __restrict__ cells,
        const int* __restrict__ rcomb,
        const int* __restrict__ LBp, const int* __restrict__ LNp,
        float* __restrict__ out) {
    __shared__ unsigned char sh_st[NB];   // 8 KB per-row status
    __shared__ int wsum[4];
    __shared__ int spec_n;
    __shared__ int spec_row[2], spec_bst[2], spec_h0[2];
    const int tid = threadIdx.x;
    const int lane = tid & 63, wid = tid >> 6;
    const int LB = *LBp, LN = *LNp;
    if (tid == 0) spec_n = 0;

    // ---- redundant full scan of all 8192 packed counts (per block) ----
    int4 v[8];
    const int base = tid * 32;
#pragma unroll
    for (int k = 0; k < 8; ++k) v[k] = ((const int4*)rcomb)[tid * 8 + k];
    const int* vv = (const int*)v;
    int rsum = 0;
#pragma unroll
    for (int k = 0; k < 32; ++k) rsum += vv[k] >> 8;
    const int incl = wave_incl_scan(rsum, lane);
    if (lane == 63) wsum[wid] = incl;
    __syncthreads();
    if (wid == 0) {
        const int orig = (lane < 4) ? wsum[lane] : 0;
        const int inc = wave_incl_scan(orig, lane);
        if (lane < 4) wsum[lane] = inc - orig;
    }
    __syncthreads();
    const int runb0 = wsum[wid] + incl - rsum;
    // pass B: per-thread hit sum (boundary rows via slow path)
    int runb = runb0, hsum = 0;
#pragma unroll
    for (int k = 0; k < 32; ++k) {
        const int val = vv[k];
        const int rc = val >> 8, hr = val & 0xff;
        int hc;
        if (runb >= LB) hc = 0;
        else if (runb + rc <= LB) hc = hr;
        else hc = slow_boundary_hits(ccount, cells, centers, radii, base + k,
                                     LB - runb);
        hsum += hc;
        runb += rc;
    }
    __syncthreads();  // wsum reuse
    const int incl2 = wave_incl_scan(hsum, lane);
    if (lane == 63) wsum[wid] = incl2;
    __syncthreads();
    if (wid == 0) {
        const int orig = (lane < 4) ? wsum[lane] : 0;
        const int inc = wave_incl_scan(orig, lane);
        if (lane < 4) wsum[lane] = inc - orig;
    }
    __syncthreads();
    int runh = wsum[wid] + incl2 - hsum;
    // pass C: status per row (recompute hc), spec capture
    runb = runb0;
#pragma unroll
    for (int k = 0; k < 32; ++k) {
        const int i = base + k;
        const int val = vv[k];
        const int rc = val >> 8, hr = val & 0xff;
        int hc;
        if (runb >= LB) hc = 0;
        else if (runb + rc <= LB) hc = hr;
        else hc = slow_boundary_hits(ccount, cells, centers, radii, i, LB - runb);
        unsigned char st = 0;
        if (hc > 0 && runh < LN) {
            const bool bfast = (runb + rc <= LB);
            const bool nfast = (runh + hc <= LN);
            if (bfast && nfast) st = 1;
            else {
                const int n = atomicAdd(&spec_n, 1);
                if (n < 2) { spec_row[n] = i; spec_bst[n] = runb; spec_h0[n] = runh; }
            }
        }
        sh_st[i] = st;
        runb += rc;
        runh += hc;
    }
    __syncthreads();

    const int row_lo = blockIdx.x * RPB;
    const int row_hi = min(NB, row_lo + RPB);

    // ---- wave 0: exact resolve of boundary rows owned by this block ----
    if (tid < 64) {
        const int ns = min(spec_n, 2);
        for (int sp = 0; sp < ns; ++sp) {
            const int i = spec_row[sp];
            if (i < row_lo || i >= row_hi) continue;
            const int blim = LB - spec_bst[sp];
            const int h0 = spec_h0[sp];
            const float2 ci = centers[i];
            const float ri = radii[i];
            const int cx = cell_of(ci.x), cy = cell_of(ci.y);
            const int x0 = max(cx - 1, 0), x1 = min(cx + 1, GRID_DIM - 1);
            const int y0 = max(cy - 1, 0), y1 = min(cy + 1, GRID_DIM - 1);
            int seg0[9], slen[9], nseg = 0, K = 0;
            for (int yy = y0; yy <= y1; ++yy)
                for (int xx = x0; xx <= x1; ++xx) {
                    const int c = yy * GRID_DIM + xx;
                    const int n = min(ccount[c], CAP);
                    if (n > 0) { seg0[nseg] = c * CAP; slen[nseg] = n; K += n; ++nseg; }
                }
            float accx = 0.f, accy = 0.f;
            for (int cb = 0; cb < K; cb += 64) {
                const int e = cb + lane;
                const bool ok = e < K;
                int s = 0;
                if (ok) {
                    int r = e;
                    for (int g = 0; g < nseg; ++g) {
                        if (r < slen[g]) { s = seg0[g] + r; break; }
                        r -= slen[g];
                    }
                }
                const float4 o = ok ? cells[s] : make_float4(0, 0, 0, __int_as_float(-1));
                const int j = __float_as_int(o.w);
                const float rs = ri + o.z, dx = o.x - ci.x, dy = o.y - ci.y;
                const bool ov = ok && j > i && fabsf(dx) <= rs && fabsf(dy) <= rs;
                if (ov) {
                    const float dist = sqrtf(dx * dx + dy * dy + EPS);
                    const float depth = rs - dist;
                    int brank = 0, hrank = 0;
                    for (int e2 = 0; e2 < K; ++e2) {  // uniform, broadcast loads
                        int r2 = e2, s2 = 0;
                        for (int g = 0; g < nseg; ++g) {
                            if (r2 < slen[g]) { s2 = seg0[g] + r2; break; }
                            r2 -= slen[g];
                        }
                        const float4 o2 = cells[s2];
                        const int j2 = __float_as_int(o2.w);
                        if (j2 <= i || j2 >= j) continue;
                        const float rs2 = ri + o2.z;
                        const float dx2 = o2.x - ci.x, dy2 = o2.y - ci.y;
                        if (fabsf(dx2) <= rs2 && fabsf(dy2) <= rs2) {
                            ++brank;
                            if (rs2 - sqrtf(dx2 * dx2 + dy2 * dy2 + EPS) > 0.f) ++hrank;
                        }
                    }
                    if (depth > 0.f && brank < blim && h0 + hrank < LN) {
                        const float sc = 0.5f * depth / dist;
                        const float px = sc * dx, py = sc * dy;
                        accx -= px; accy -= py;
                        atomicAdd(&out[2 * j], px);
                        atomicAdd(&out[2 * j + 1], py);
                    }
                }
            }
#pragma unroll
            for (int off = 32; off > 0; off >>= 1) {
                accx += __shfl_down(accx, off);
                accy += __shfl_down(accy, off);
            }
            if (lane == 0 && (accx != 0.f || accy != 0.f)) {
                atomicAdd(&out[2 * i], accx);
                atomicAdd(&out[2 * i + 1], accy);
            }
        }
    }

    // ---- fast-row resolve: rows [row_lo,row_hi), 3 threads/row ----
    for (int u = tid; u < RPB * 3; u += 256) {
        const int i = row_lo + u / 3;
        if (i >= row_hi) break;
        if (!sh_st[i]) continue;
        const int seg = u % 3;
        const float2 ci = centers[i];
        const float ri = radii[i];
        const int cx = cell_of(ci.x), cy = cell_of(ci.y);
        const int yy = cy - 1 + seg;
        if (yy < 0 || yy >= GRID_DIM) continue;
        const int x0 = max(cx - 1, 0), x1 = min(cx + 1, GRID_DIM - 1);
        float accx = 0.f, accy = 0.f;
        for (int xx = x0; xx <= x1; ++xx) {
            const int c = yy * GRID_DIM + xx;
            const int n = min(ccount[c], CAP);
            const float4* p = cells + c * CAP;
            for (int k = 0; k < n; ++k) {
                const float4 o = p[k];
                const int j = __float_as_int(o.w);
                if (j <= i) continue;
                const float rs = ri + o.z;
                const float dx = o.x - ci.x, dy = o.y - ci.y;
                if (!(fabsf(dx) <= rs && fabsf(dy) <= rs)) continue;
                const float dist = sqrtf(dx * dx + dy * dy + EPS);
                const float depth = rs - dist;
                if (depth <= 0.f) continue;
                const float sc = 0.5f * depth / dist;
                const float px = sc * dx, py = sc * dy;
                accx -= px; accy -= py;
                atomicAdd(&out[2 * j], px);
                atomicAdd(&out[2 * j + 1], py);
            }
        }
        if (accx != 0.f || accy != 0.f) {
            atomicAdd(&out[2 * i], accx);
            atomicAdd(&out[2 * i + 1], accy);
        }
    }
}

extern "C" void kernel_launch(void* const* d_in, const int* in_sizes, int n_in,
                              void* d_out, int out_size, void* d_ws, size_t ws_size,
                              hipStream_t stream) {
    const float2* centers = (const float2*)d_in[0];
    const float* radii    = (const float*)d_in[1];
    const int* LBp = (const int*)d_in[2];
    const int* LNp = (const int*)d_in[3];
    float* out = (float*)d_out;

    int* ws = (int*)d_ws;
    int* ccount = ws + O_CCOUNT;
    int* rcomb  = ws + O_RCOMB;
    float4* cells = (float4*)(ws + O_CELLS);

    hipMemsetAsync(ccount, 0, NCELLS * sizeof(int), stream);
    fill_kernel<<<NB / 256, 256, 0, stream>>>(centers, radii, ccount, cells,
                                              rcomb, (float2*)out);
    count_kernel<<<3 * NB / 256, 256, 0, stream>>>(centers, radii, ccount,
                                                   cells, rcomb);
    final_kernel<<<NBLK, 256, 0, stream>>>(centers, radii, ccount, cells,
                                           rcomb, LBp, LNp, out);
}